// Round 1
// baseline (3236.626 us; speedup 1.0000x reference)
//
#include <hip/hip_runtime.h>
#include <cmath>

#define T_STEPS 256
#define DIN  1024
#define DHID 1024
#define DOUT 1024
#define NB   128
#define BH   (DHID*NB)   // 131072 elems per h snapshot

typedef unsigned short u16;
typedef unsigned int   u32;
typedef __attribute__((ext_vector_type(8))) __bf16 bf16x8;
typedef __attribute__((ext_vector_type(4))) float  f32x4;

__device__ __forceinline__ u16 f2bf(float f){
  u32 u = __builtin_bit_cast(u32, f);
  u32 r = (u + 0x7fffu + ((u >> 16) & 1u)) >> 16;   // RNE
  return (u16)r;
}
__device__ __forceinline__ float bf2f(u16 h){
  u32 u = ((u32)h) << 16;
  return __builtin_bit_cast(float, u);
}

// ---------------- weight convert: 3x 1024x1024 fp32 -> bf16 ----------------
__global__ __launch_bounds__(256) void wconv(const float* __restrict__ w0,
                                             const float* __restrict__ w1,
                                             const float* __restrict__ w2,
                                             u16* __restrict__ dst){
  const int idx = blockIdx.x*256 + threadIdx.x;   // < 786432 (float4 units)
  const int seg = idx >> 18;                      // /262144
  const int off = idx & 262143;
  const float* src = seg==0 ? w0 : (seg==1 ? w1 : w2);
  const float4 v = ((const float4*)src)[off];
  ushort4 o = make_ushort4(f2bf(v.x), f2bf(v.y), f2bf(v.z), f2bf(v.w));
  ((ushort4*)dst)[idx] = o;
}

// ---------------- h_prev [HID][B] fp32 -> H_T[0] [B][HID] bf16 ----------------
__global__ __launch_bounds__(256) void hprevT(const float* __restrict__ hp,
                                              u16* __restrict__ HT0){
  const int tid = blockIdx.x*256 + threadIdx.x;   // < 131072
  const int b = tid >> 10, m = tid & 1023;
  HT0[tid] = f2bf(hp[(size_t)m*NB + b]);
}

// ---------------- X [T][IN][B] fp32 -> X^T [T][B][IN] bf16 ----------------
__global__ __launch_bounds__(256) void xT_k(const float* __restrict__ x,
                                            u16* __restrict__ xt){
  __shared__ float tile[64][65];
  const int t  = blockIdx.z;
  const int k0 = blockIdx.y*64;
  const int b0 = blockIdx.x*64;
  const int tx = threadIdx.x & 63, ty = threadIdx.x >> 6;  // ty 0..3
  const float* src = x + (size_t)t*DIN*NB + (size_t)k0*NB + b0;
#pragma unroll
  for(int r=0;r<16;r++){ int k = r*4 + ty; tile[k][tx] = src[(size_t)k*NB + tx]; }
  __syncthreads();
  u16* dst = xt + (size_t)t*NB*DIN + (size_t)b0*DIN + k0;
#pragma unroll
  for(int r=0;r<16;r++){ int b = r*4 + ty; dst[(size_t)b*DIN + tx] = f2bf(tile[tx][b]); }
}

// ---------------- A[t] = X^T[t] @ Wxh^T + bh  -> bf16 [T][B][HID] ----------------
// 128x128 tile, BK=32, 4 waves (2x2 of 64x64), reg-prefetch pipelined
__global__ __launch_bounds__(256) void gemm_xw(const u16* __restrict__ XT,
                                               const u16* __restrict__ WxB,
                                               const float* __restrict__ bh,
                                               u16* __restrict__ AT){
  const int t  = blockIdx.y;
  const int mj = blockIdx.x;
  __shared__ __align__(16) u16 As[128*40];
  __shared__ __align__(16) u16 Bs[128*40];
  const u16* aG = XT + (size_t)t*NB*DIN;          // rows = b (128), K-contig
  const u16* bG = WxB + (size_t)mj*128*DIN;       // rows = m slice, K-contig
  const int tid = threadIdx.x;
  const int lane = tid & 63, w = tid >> 6;
  const int wr = (w & 1)*64, wc = (w >> 1)*64;
  const int l15 = lane & 15, q = lane >> 4;
  const int sr = tid >> 2;            // 0..63
  const int sk = (tid & 3)*8;         // 0,8,16,24

  f32x4 acc[4][4] = {};
  uint4 pa0 = *(const uint4*)&aG[(size_t)sr*DIN + sk];
  uint4 pa1 = *(const uint4*)&aG[(size_t)(sr+64)*DIN + sk];
  uint4 pb0 = *(const uint4*)&bG[(size_t)sr*DIN + sk];
  uint4 pb1 = *(const uint4*)&bG[(size_t)(sr+64)*DIN + sk];

  for(int it = 0; it < DIN/32; ++it){
    __syncthreads();
    *(uint4*)&As[sr*40 + sk]      = pa0;
    *(uint4*)&As[(sr+64)*40 + sk] = pa1;
    *(uint4*)&Bs[sr*40 + sk]      = pb0;
    *(uint4*)&Bs[(sr+64)*40 + sk] = pb1;
    __syncthreads();
    if(it < DIN/32 - 1){
      const int k0 = (it+1)*32;
      pa0 = *(const uint4*)&aG[(size_t)sr*DIN + k0 + sk];
      pa1 = *(const uint4*)&aG[(size_t)(sr+64)*DIN + k0 + sk];
      pb0 = *(const uint4*)&bG[(size_t)sr*DIN + k0 + sk];
      pb1 = *(const uint4*)&bG[(size_t)(sr+64)*DIN + k0 + sk];
    }
    bf16x8 af[4], bf[4];
#pragma unroll
    for(int i=0;i<4;i++) af[i] = *(const bf16x8*)&As[(wr + i*16 + l15)*40 + q*8];
#pragma unroll
    for(int j=0;j<4;j++) bf[j] = *(const bf16x8*)&Bs[(wc + j*16 + l15)*40 + q*8];
#pragma unroll
    for(int i=0;i<4;i++)
#pragma unroll
      for(int j=0;j<4;j++)
        acc[i][j] = __builtin_amdgcn_mfma_f32_16x16x32_bf16(af[i], bf[j], acc[i][j], 0,0,0);
  }

  u16* out = AT + (size_t)t*NB*DHID;
#pragma unroll
  for(int j=0;j<4;j++){
    const int mg = mj*128 + wc + j*16 + l15;
    const float bhv = bh[mg];
#pragma unroll
    for(int i=0;i<4;i++){
#pragma unroll
      for(int r=0;r<4;r++){
        const int bg = wr + i*16 + q*4 + r;     // D row = A-operand m-index (=b here)
        out[(size_t)bg*DHID + mg] = f2bf(acc[i][j][r] + bhv);
      }
    }
  }
}

// ---------------- one recurrence step: H_T[t+1] = tanh(A[t] + H_T[t] @ Whh^T) ----------------
// tile 32(b) x 64(m), BK=64, 4 waves (2x2 of 16x32), reg-prefetch pipelined
__global__ __launch_bounds__(256) void step_k(const u16* __restrict__ Hprev,
                                              const u16* __restrict__ WhB,
                                              const u16* __restrict__ ATt,
                                              u16* __restrict__ Hnext){
  const int mt = blockIdx.x;   // 0..15
  const int bt = blockIdx.y;   // 0..3
  __shared__ __align__(16) u16 As[32*72];
  __shared__ __align__(16) u16 Bs[64*72];
  const u16* aG = Hprev + (size_t)bt*32*DHID;
  const u16* bG = WhB  + (size_t)mt*64*DHID;
  const int tid = threadIdx.x;
  const int lane = tid & 63, w = tid >> 6;
  const int wr = (w & 1)*16, wc = (w >> 1)*32;
  const int l15 = lane & 15, q = lane >> 4;
  const int sr = tid >> 3;        // 0..31
  const int sk = (tid & 7)*8;     // 0..56

  f32x4 acc[2] = {};
  uint4 pa  = *(const uint4*)&aG[(size_t)sr*DHID + sk];
  uint4 pb0 = *(const uint4*)&bG[(size_t)sr*DHID + sk];
  uint4 pb1 = *(const uint4*)&bG[(size_t)(sr+32)*DHID + sk];

  for(int it=0; it<DHID/64; ++it){
    __syncthreads();
    *(uint4*)&As[sr*72 + sk]      = pa;
    *(uint4*)&Bs[sr*72 + sk]      = pb0;
    *(uint4*)&Bs[(sr+32)*72 + sk] = pb1;
    __syncthreads();
    if(it < DHID/64 - 1){
      const int k0 = (it+1)*64;
      pa  = *(const uint4*)&aG[(size_t)sr*DHID + k0 + sk];
      pb0 = *(const uint4*)&bG[(size_t)sr*DHID + k0 + sk];
      pb1 = *(const uint4*)&bG[(size_t)(sr+32)*DHID + k0 + sk];
    }
#pragma unroll
    for(int s=0;s<2;s++){
      bf16x8 a = *(const bf16x8*)&As[(wr + l15)*72 + s*32 + q*8];
#pragma unroll
      for(int j=0;j<2;j++){
        bf16x8 bb = *(const bf16x8*)&Bs[(wc + j*16 + l15)*72 + s*32 + q*8];
        acc[j] = __builtin_amdgcn_mfma_f32_16x16x32_bf16(a, bb, acc[j], 0,0,0);
      }
    }
  }
#pragma unroll
  for(int j=0;j<2;j++){
    const int mg = mt*64 + wc + j*16 + l15;
#pragma unroll
    for(int r=0;r<4;r++){
      const int bg = bt*32 + wr + q*4 + r;
      const float v = acc[j][r] + bf2f(ATt[(size_t)bg*DHID + mg]);
      Hnext[(size_t)bg*DHID + mg] = f2bf(tanhf(v));
    }
  }
}

// ---------------- Y[t] = Why @ h_t + by  -> fp32 [T][OUT][B] ----------------
__global__ __launch_bounds__(256) void gemm_hy(const u16* __restrict__ WyB,
                                               const u16* __restrict__ HT,
                                               const float* __restrict__ by,
                                               float* __restrict__ Y){
  const int t  = blockIdx.y;
  const int mi = blockIdx.x;
  __shared__ __align__(16) u16 As[128*40];
  __shared__ __align__(16) u16 Bs[128*40];
  const u16* aG = WyB + (size_t)mi*128*DHID;       // rows = out slice
  const u16* bG = HT  + (size_t)(t+1)*BH;          // rows = b (128)
  const int tid = threadIdx.x;
  const int lane = tid & 63, w = tid >> 6;
  const int wr = (w & 1)*64, wc = (w >> 1)*64;
  const int l15 = lane & 15, q = lane >> 4;
  const int sr = tid >> 2;
  const int sk = (tid & 3)*8;

  f32x4 acc[4][4] = {};
  uint4 pa0 = *(const uint4*)&aG[(size_t)sr*DHID + sk];
  uint4 pa1 = *(const uint4*)&aG[(size_t)(sr+64)*DHID + sk];
  uint4 pb0 = *(const uint4*)&bG[(size_t)sr*DHID + sk];
  uint4 pb1 = *(const uint4*)&bG[(size_t)(sr+64)*DHID + sk];

  for(int it = 0; it < DHID/32; ++it){
    __syncthreads();
    *(uint4*)&As[sr*40 + sk]      = pa0;
    *(uint4*)&As[(sr+64)*40 + sk] = pa1;
    *(uint4*)&Bs[sr*40 + sk]      = pb0;
    *(uint4*)&Bs[(sr+64)*40 + sk] = pb1;
    __syncthreads();
    if(it < DHID/32 - 1){
      const int k0 = (it+1)*32;
      pa0 = *(const uint4*)&aG[(size_t)sr*DHID + k0 + sk];
      pa1 = *(const uint4*)&aG[(size_t)(sr+64)*DHID + k0 + sk];
      pb0 = *(const uint4*)&bG[(size_t)sr*DHID + k0 + sk];
      pb1 = *(const uint4*)&bG[(size_t)(sr+64)*DHID + k0 + sk];
    }
    bf16x8 af[4], bf[4];
#pragma unroll
    for(int i=0;i<4;i++) af[i] = *(const bf16x8*)&As[(wr + i*16 + l15)*40 + q*8];
#pragma unroll
    for(int j=0;j<4;j++) bf[j] = *(const bf16x8*)&Bs[(wc + j*16 + l15)*40 + q*8];
#pragma unroll
    for(int i=0;i<4;i++)
#pragma unroll
      for(int j=0;j<4;j++)
        acc[i][j] = __builtin_amdgcn_mfma_f32_16x16x32_bf16(af[i], bf[j], acc[i][j], 0,0,0);
  }

  float* out = Y + (size_t)t*DOUT*NB;
#pragma unroll
  for(int i=0;i<4;i++){
#pragma unroll
    for(int r=0;r<4;r++){
      const int og = mi*128 + wr + i*16 + q*4 + r;  // D row = out index
      const float byv = by[og];
#pragma unroll
      for(int j=0;j<4;j++){
        const int bg = wc + j*16 + l15;             // D col = batch index
        out[(size_t)og*NB + bg] = acc[i][j][r] + byv;
      }
    }
  }
}

// ---------------- h_final: H_T[T] [B][HID] bf16 -> [HID][B] fp32 ----------------
__global__ __launch_bounds__(256) void hfinal(const u16* __restrict__ HT,
                                              float* __restrict__ dst){
  const int tid = blockIdx.x*256 + threadIdx.x;   // < 131072
  const int m = tid >> 7, b = tid & 127;
  dst[tid] = bf2f(HT[(size_t)T_STEPS*BH + (size_t)b*DHID + m]);
}

extern "C" void kernel_launch(void* const* d_in, const int* in_sizes, int n_in,
                              void* d_out, int out_size, void* d_ws, size_t ws_size,
                              hipStream_t stream)
{
  const float* x   = (const float*)d_in[0];   // [T, IN, B]
  const float* hp  = (const float*)d_in[1];   // [HID, B]
  const float* wxh = (const float*)d_in[2];   // [HID, IN]
  const float* whh = (const float*)d_in[3];   // [HID, HID]
  const float* why = (const float*)d_in[4];   // [OUT, HID]
  const float* bh  = (const float*)d_in[5];   // [HID, 1]
  const float* by  = (const float*)d_in[6];   // [OUT, 1]
  float* out = (float*)d_out;

  // workspace: bf16 weights (6 MB) + H_T (T+1 snapshots, 64.25 MB)
  u16* WxB = (u16*)d_ws;
  u16* WhB = WxB + (size_t)1024*1024;
  u16* WyB = WhB + (size_t)1024*1024;
  u16* HT  = WyB + (size_t)1024*1024;

  // temporaries inside d_out (dead before gemm_hy overwrites):
  //   X^T bf16 at bytes [0, 64MB), A bf16 at [64MB, 128MB); y region is 128MB, tail after.
  u16* XT = (u16*)d_out;
  u16* AT = XT + (size_t)T_STEPS*NB*DIN;

  wconv  <<<3072, 256, 0, stream>>>(wxh, whh, why, WxB);
  hprevT <<<512,  256, 0, stream>>>(hp, HT);
  xT_k   <<<dim3(2,16,T_STEPS), 256, 0, stream>>>(x, XT);
  gemm_xw<<<dim3(8,T_STEPS),    256, 0, stream>>>(XT, WxB, bh, AT);
  for(int t=0;t<T_STEPS;t++)
    step_k<<<dim3(16,4), 256, 0, stream>>>(HT + (size_t)t*BH, WhB,
                                           AT + (size_t)t*BH, HT + (size_t)(t+1)*BH);
  gemm_hy<<<dim3(8,T_STEPS), 256, 0, stream>>>(WyB, HT, by, out);
  hfinal <<<512, 256, 0, stream>>>(HT, out + (size_t)T_STEPS*DOUT*NB);
}